// Round 5
// baseline (587.150 us; speedup 1.0000x reference)
//
#include <hip/hip_runtime.h>

#define NN 100000
#define NE 1600000
#define SCAN_BLK 2048

#define BSH 9                                  // 512 nodes/bucket
#define NBUCK2 ((NN + 511) / 512)              // 196 coarse buckets
#define CHUNK 8192                             // edges per partition block
#define NCHK ((NE + CHUNK - 1) / CHUNK)        // 196 chunks
#define L2T (NBUCK2 * NCHK)                    // 38416
#define NSTRIP (NN / 32)                       // 3125 exact

using bf16x8 = __attribute__((ext_vector_type(8))) short;
using f32x16 = __attribute__((ext_vector_type(16))) float;

// ---- bf16 helpers (RNE) ----
__device__ __forceinline__ unsigned short f2bf(float f) {
    unsigned u = __float_as_uint(f);
    u += 0x7FFFu + ((u >> 16) & 1u);
    return (unsigned short)(u >> 16);
}
__device__ __forceinline__ float bf2f(unsigned short h) {
    return __uint_as_float(((unsigned)h) << 16);
}

// ---------------- per-chunk bucket histogram (LDS only) ----------------
__global__ __launch_bounds__(256) void hist2_kernel(const int* __restrict__ dst,
                                                    int* __restrict__ histm) {
    __shared__ int lh[256];
    int blk = blockIdx.x, tid = threadIdx.x;
    lh[tid] = 0;
    __syncthreads();
    int base = blk * CHUNK;
#pragma unroll
    for (int t = 0; t < CHUNK / 256; t++) {
        int e = base + t * 256 + tid;
        if (e < NE) atomicAdd(&lh[dst[e] >> BSH], 1);
    }
    __syncthreads();
    if (tid < NBUCK2) histm[tid * NCHK + blk] = lh[tid];   // bucket-major
}

// ---------------- exclusive scan, stage 1 ----------------
__global__ __launch_bounds__(256) void scan1_kernel(int* __restrict__ data,
                                                    int* __restrict__ bsums, int L) {
    __shared__ int s[256];
    int bid = blockIdx.x, tid = threadIdx.x;
    int base = bid * SCAN_BLK + tid * 8;
    int v[8];
    int sum = 0;
#pragma unroll
    for (int t = 0; t < 8; t++) {
        int idx = base + t;
        v[t] = (idx < L) ? data[idx] : 0;
        sum += v[t];
    }
    s[tid] = sum;
    __syncthreads();
    for (int off = 1; off < 256; off <<= 1) {
        int val = (tid >= off) ? s[tid - off] : 0;
        __syncthreads();
        s[tid] += val;
        __syncthreads();
    }
    int excl = s[tid] - sum;
    if (tid == 255) bsums[bid] = s[255];
    int run = excl;
#pragma unroll
    for (int t = 0; t < 8; t++) {
        int idx = base + t;
        if (idx < L) data[idx] = run;
        run += v[t];
    }
}

// ---------------- scan stage 2: one wave over n<=64 sums ----------------
__global__ __launch_bounds__(64) void scan2_kernel(int* __restrict__ bsums, int n) {
    int tid = threadIdx.x;
    int orig = (tid < n) ? bsums[tid] : 0;
    int v = orig;
    for (int off = 1; off < 64; off <<= 1) {
        int nb = __shfl_up(v, off, 64);
        if (tid >= off) v += nb;
    }
    if (tid < n) bsums[tid] = v - orig;
}

// ---------------- add offsets (histm) ----------------
__global__ __launch_bounds__(256) void scan_add_kernel(int* __restrict__ data,
                                                       const int* __restrict__ bsums, int L) {
    int i = blockIdx.x * 256 + threadIdx.x;
    if (i < L) data[i] += bsums[i / SCAN_BLK];
}

// ---------------- deterministic coarse scatter (LDS cursors) ----------------
__global__ __launch_bounds__(256) void scatter2_kernel(const int* __restrict__ src,
                                                       const int* __restrict__ dst,
                                                       const int* __restrict__ histm,
                                                       int* __restrict__ tmp) {
    __shared__ int lcur[256];
    int blk = blockIdx.x, tid = threadIdx.x;
    if (tid < NBUCK2) lcur[tid] = histm[tid * NCHK + blk];
    __syncthreads();
    int base = blk * CHUNK;
#pragma unroll
    for (int t = 0; t < CHUNK / 256; t++) {
        int e = base + t * 256 + tid;
        if (e < NE) {
            int d = dst[e];
            int p = atomicAdd(&lcur[d >> BSH], 1);      // LDS atomic
            tmp[p] = src[e] | ((d & 511) << 17);        // src<2^17
        }
    }
}

// ---------------- fused count + scan + place per bucket ----------------
__global__ __launch_bounds__(256) void count_place_kernel(const int* __restrict__ histm,
                                                          const int* __restrict__ tmp,
                                                          int* __restrict__ rowptr,
                                                          int* __restrict__ esrc) {
    __shared__ int cnt[512];   // counts, then cursors
    __shared__ int s[256];
    int b = blockIdx.x, tid = threadIdx.x;
    int beg = histm[b * NCHK];
    int end = (b == NBUCK2 - 1) ? NE : histm[(b + 1) * NCHK];

    cnt[tid] = 0; cnt[tid + 256] = 0;
    __syncthreads();
    for (int e = beg + tid; e < end; e += 256)
        atomicAdd(&cnt[tmp[e] >> 17], 1);               // LDS atomic
    __syncthreads();

    int c0 = cnt[2 * tid], c1 = cnt[2 * tid + 1];
    int sum = c0 + c1;
    s[tid] = sum;
    __syncthreads();
    for (int off = 1; off < 256; off <<= 1) {
        int val = (tid >= off) ? s[tid - off] : 0;
        __syncthreads();
        s[tid] += val;
        __syncthreads();
    }
    int o0 = beg + s[tid] - sum;                        // exclusive
    int o1 = o0 + c0;
    cnt[2 * tid] = o0;                                  // cursors
    cnt[2 * tid + 1] = o1;
    int node0 = (b << BSH) + 2 * tid;
    if (node0 < NN)     rowptr[node0]     = o0;
    if (node0 + 1 < NN) rowptr[node0 + 1] = o1;
    if (b == 0 && tid == 0) rowptr[NN] = NE;
    __syncthreads();

    for (int e = beg + tid; e < end; e += 256) {
        int v = tmp[e];
        int p = atomicAdd(&cnt[v >> 17], 1);            // LDS atomic
        esrc[p] = v & 0x1FFFF;
    }
}

// ---------------- fp32 -> bf16 convert ----------------
__global__ __launch_bounds__(256) void cvt_kernel(const float* __restrict__ in,
                                                  unsigned short* __restrict__ out, int n4) {
    int i = blockIdx.x * 256 + threadIdx.x;
    if (i < n4) {
        float4 f = ((const float4*)in)[i];
        ((ushort4*)out)[i] = make_ushort4(f2bf(f.x), f2bf(f.y), f2bf(f.z), f2bf(f.w));
    }
}

// ---------------- bf16 mean-aggregate, K=64 ----------------
// Wave per node. 8 lanes/edge x 16B (bf16x8) = 128B row; 8 edges per load
// instruction; x2 unroll = 16 edges (2KB) in flight.
__global__ __launch_bounds__(256) void agg64_kernel(const unsigned short* __restrict__ feat,
                                                    const int* __restrict__ rowptr,
                                                    const int* __restrict__ esrc,
                                                    unsigned short* __restrict__ agg) {
    int node = blockIdx.x * 4 + (threadIdx.x >> 6);
    int lane = threadIdx.x & 63;
    int es = lane >> 3;            // edge slot 0..7
    int fi = lane & 7;             // feature block (8 bf16)
    int beg = rowptr[node], end = rowptr[node + 1];

    float ax[8];
#pragma unroll
    for (int i = 0; i < 8; i++) ax[i] = 0.0f;

    int e = beg;
    for (; e + 15 < end; e += 16) {
        int sA = esrc[e + es];
        int sB = esrc[e + 8 + es];
        bf16x8 uA = *(const bf16x8*)(feat + (size_t)sA * 64 + fi * 8);
        bf16x8 uB = *(const bf16x8*)(feat + (size_t)sB * 64 + fi * 8);
#pragma unroll
        for (int i = 0; i < 8; i++)
            ax[i] += bf2f((unsigned short)uA[i]) + bf2f((unsigned short)uB[i]);
    }
    if (e + 7 < end) {
        int s = esrc[e + es];
        bf16x8 u = *(const bf16x8*)(feat + (size_t)s * 64 + fi * 8);
#pragma unroll
        for (int i = 0; i < 8; i++) ax[i] += bf2f((unsigned short)u[i]);
        e += 8;
    }
    if (es < end - e) {
        int s = esrc[e + es];
        bf16x8 u = *(const bf16x8*)(feat + (size_t)s * 64 + fi * 8);
#pragma unroll
        for (int i = 0; i < 8; i++) ax[i] += bf2f((unsigned short)u[i]);
    }

#pragma unroll
    for (int i = 0; i < 8; i++) {
        ax[i] += __shfl_xor(ax[i], 8);
        ax[i] += __shfl_xor(ax[i], 16);
        ax[i] += __shfl_xor(ax[i], 32);
    }
    if (es == 0) {
        float inv = 1.0f / fmaxf((float)(end - beg), 1.0f);
        bf16x8 o;
#pragma unroll
        for (int i = 0; i < 8; i++) o[i] = (short)f2bf(ax[i] * inv);
        *(bf16x8*)(agg + (size_t)node * 64 + fi * 8) = o;
    }
}

// ---------------- bf16 mean-aggregate, K=128, feature-split v2 ----------------
// Table hbT is column-block-major [8][NN][16] bf16 (3.2 MB / block); output
// aggT same layout. c = blockIdx&7 == XCD (round-robin dispatch) -> each
// XCD's gather slice is L2-resident (proven round 4: FETCH 178->65 MB).
// v2 schedule fix: ONE NODE PER WAVE (no intra-wave multi-node divergence),
// es = lane>>1 gives 32 edge slots x 32B -> deg~16 completes in a single
// masked iteration; esrc reads are 128B contiguous per wave. Reduce over es
// via shfl_xor 2/4/8/16/32 (parity-preserving, fi = lane&1 intact).
__global__ __launch_bounds__(256) void agg128_split_kernel(
    const unsigned short* __restrict__ hbT,
    const int* __restrict__ rowptr,
    const int* __restrict__ esrc,
    unsigned short* __restrict__ aggT) {
    int c = blockIdx.x & 7;        // col-block == XCD
    int node = (blockIdx.x >> 3) * 4 + (threadIdx.x >> 6);
    int lane = threadIdx.x & 63;
    int es = lane >> 1;            // edge slot 0..31
    int fi = lane & 1;             // 8-col half of the 16-col block
    int beg = rowptr[node], end = rowptr[node + 1];

    const unsigned short* tab = hbT + (size_t)c * NN * 16 + fi * 8;

    float ax[8];
#pragma unroll
    for (int i = 0; i < 8; i++) ax[i] = 0.0f;

    for (int e = beg + es; e < end; e += 32) {
        int s = esrc[e];
        bf16x8 u = *(const bf16x8*)(tab + (size_t)s * 16);
#pragma unroll
        for (int i = 0; i < 8; i++) ax[i] += bf2f((unsigned short)u[i]);
    }

#pragma unroll
    for (int i = 0; i < 8; i++) {
        ax[i] += __shfl_xor(ax[i], 2);
        ax[i] += __shfl_xor(ax[i], 4);
        ax[i] += __shfl_xor(ax[i], 8);
        ax[i] += __shfl_xor(ax[i], 16);
        ax[i] += __shfl_xor(ax[i], 32);
    }
    if (es == 0) {
        float inv = 1.0f / fmaxf((float)(end - beg), 1.0f);
        bf16x8 o;
#pragma unroll
        for (int i = 0; i < 8; i++) o[i] = (short)f2bf(ax[i] * inv);
        *(bf16x8*)(aggT + (size_t)c * NN * 16 + (size_t)node * 16 + fi * 8) = o;
    }
}

// ---------------- MFMA GEMM: out[n,0:128] = A1@Wa.T + A2@Wb.T + bias ----------------
// A1SPLIT/A2SPLIT: operand is column-block-major [K/16][NN][16] (hbT layout) —
// the 8-bf16 fragment at col offset kc+half*8 never crosses a 16-col chunk.
// OUTSPLIT: write hbT layout. C/D map (m74/m101): col=lane&31,
// row=(reg&3)+8*(reg>>2)+4*half.
template <int K, bool RELU, bool OUTBF, bool A1SPLIT, bool A2SPLIT, bool OUTSPLIT>
__global__ __launch_bounds__(256) void gemm_mfma_kernel(
    const unsigned short* __restrict__ A1,
    const unsigned short* __restrict__ A2,
    const unsigned short* __restrict__ Wa,
    const unsigned short* __restrict__ Wb,
    const float* __restrict__ bias,
    void* __restrict__ outv) {
    int strip = blockIdx.x * 4 + (threadIdx.x >> 6);
    if (strip >= NSTRIP) return;
    const int lane = threadIdx.x & 63;
    const int m = lane & 31;
    const int half = lane >> 5;
    const int base = strip * 32;

    f32x16 acc[4];
#pragma unroll
    for (int nb = 0; nb < 4; ++nb)
#pragma unroll
        for (int r = 0; r < 16; ++r) acc[nb][r] = 0.0f;

#pragma unroll
    for (int kc = 0; kc < K; kc += 16) {
        bf16x8 a;
        if (A1SPLIT) {
            int off = kc + half * 8;
            a = *(const bf16x8*)(A1 + (size_t)(off >> 4) * NN * 16 +
                                 (size_t)(base + m) * 16 + (off & 15));
        } else {
            a = *(const bf16x8*)(A1 + (size_t)(base + m) * K + half * 8 + kc);
        }
#pragma unroll
        for (int nb = 0; nb < 4; ++nb) {
            bf16x8 b = *(const bf16x8*)(Wa + (size_t)(nb * 32 + m) * K + kc + half * 8);
            acc[nb] = __builtin_amdgcn_mfma_f32_32x32x16_bf16(a, b, acc[nb], 0, 0, 0);
        }
    }
#pragma unroll
    for (int kc = 0; kc < K; kc += 16) {
        bf16x8 a;
        if (A2SPLIT) {
            int off = kc + half * 8;
            a = *(const bf16x8*)(A2 + (size_t)(off >> 4) * NN * 16 +
                                 (size_t)(base + m) * 16 + (off & 15));
        } else {
            a = *(const bf16x8*)(A2 + (size_t)(base + m) * K + half * 8 + kc);
        }
#pragma unroll
        for (int nb = 0; nb < 4; ++nb) {
            bf16x8 b = *(const bf16x8*)(Wb + (size_t)(nb * 32 + m) * K + kc + half * 8);
            acc[nb] = __builtin_amdgcn_mfma_f32_32x32x16_bf16(a, b, acc[nb], 0, 0, 0);
        }
    }

#pragma unroll
    for (int nb = 0; nb < 4; ++nb) {
        int j = nb * 32 + m;
        float bz = bias[j];
#pragma unroll
        for (int r = 0; r < 16; ++r) {
            int row = (r & 3) + 8 * (r >> 2) + 4 * half;
            float v = acc[nb][r] + bz;
            if (RELU) v = fmaxf(v, 0.0f);
            if (OUTSPLIT) {
                size_t idx = (size_t)(j >> 4) * NN * 16 + (size_t)(base + row) * 16 + (j & 15);
                ((unsigned short*)outv)[idx] = f2bf(v);
            } else {
                size_t idx = (size_t)(base + row) * 128 + j;
                if (OUTBF) ((unsigned short*)outv)[idx] = f2bf(v);
                else       ((float*)outv)[idx] = v;
            }
        }
    }
}

extern "C" void kernel_launch(void* const* d_in, const int* in_sizes, int n_in,
                              void* d_out, int out_size, void* d_ws, size_t ws_size,
                              hipStream_t stream) {
    const float* x   = (const float*)d_in[0];
    const int*   ei  = (const int*)d_in[1];
    const float* W1l = (const float*)d_in[2];
    const float* W1r = (const float*)d_in[3];
    const float* b1  = (const float*)d_in[4];
    const float* W2l = (const float*)d_in[5];
    const float* W2r = (const float*)d_in[6];
    const float* b2  = (const float*)d_in[7];
    float* out = (float*)d_out;

    const int* src = ei;        // edge_index[0]
    const int* dst = ei + NE;   // edge_index[1]

    // ---- workspace layout ----
    char* ws = (char*)d_ws;
    int* rowptr = (int*)ws;                                  // [0, 401408)
    int* esrc   = (int*)(ws + 401408);                       // NE ints
    unsigned short* aggB = (unsigned short*)(ws + 6803456);  // NN*128 bf16 (25.6 MB)
    unsigned short* xb   = aggB + (size_t)NN * 64;           // NN*64 bf16, aggB upper half
    char* E = ws + 32403456;                                 // 25.6 MB region
    unsigned short* hbT = (unsigned short*)E;                // [8][NN][16] bf16 col-block-major
    int* tmp   = (int*)E;                                    // NE ints (transient)
    int* histm = (int*)(E + 6400000);                        // L2T ints (transient)
    int* bsums = (int*)(E + 6560000);                        // <=64 ints (transient)
    // W bf16 copies:
    unsigned short* W1lb = (unsigned short*)d_out;           // 128*64 bf16 (16 KB)
    unsigned short* W1rb = W1lb + 128 * 64;
    unsigned short* W2lb = (unsigned short*)ws;              // 128*128 bf16 (32 KB), after agg128
    unsigned short* W2rb = W2lb + 128 * 128;

    const int GB  = (NSTRIP + 3) / 4;                        // 782 gemm blocks
    const int NSB2 = (L2T + SCAN_BLK - 1) / SCAN_BLK;        // 19

    // ---- build CSR (edge list sorted by dst); no global atomics ----
    hist2_kernel<<<NCHK, 256, 0, stream>>>(dst, histm);
    scan1_kernel<<<NSB2, 256, 0, stream>>>(histm, bsums, L2T);
    scan2_kernel<<<1, 64, 0, stream>>>(bsums, NSB2);
    scan_add_kernel<<<(L2T + 255) / 256, 256, 0, stream>>>(histm, bsums, L2T);
    scatter2_kernel<<<NCHK, 256, 0, stream>>>(src, dst, histm, tmp);
    count_place_kernel<<<NBUCK2, 256, 0, stream>>>(histm, tmp, rowptr, esrc);

    // ---- bf16 planes ----
    cvt_kernel<<<(NN * 64 / 4 + 255) / 256, 256, 0, stream>>>(x, xb, NN * 64 / 4);
    cvt_kernel<<<(128 * 64 / 4 + 255) / 256, 256, 0, stream>>>(W1l, W1lb, 128 * 64 / 4);
    cvt_kernel<<<(128 * 64 / 4 + 255) / 256, 256, 0, stream>>>(W1r, W1rb, 128 * 64 / 4);

    // ---- layer 1: hbT = split(bf16(relu(mean(agg) @ W1l.T + x @ W1r.T + b1))) ----
    agg64_kernel<<<NN / 4, 256, 0, stream>>>(xb, rowptr, esrc, aggB);
    gemm_mfma_kernel<64, true, true, false, false, true><<<GB, 256, 0, stream>>>(
        aggB, xb, W1lb, W1rb, b1, hbT);

    // ---- layer 2: out = mean(agg2) @ W2l.T + h @ W2r.T + b2 ----
    agg128_split_kernel<<<(NN / 4) * 8, 256, 0, stream>>>(hbT, rowptr, esrc, aggB);
    cvt_kernel<<<(128 * 128 / 4 + 255) / 256, 256, 0, stream>>>(W2l, W2lb, 128 * 128 / 4);
    cvt_kernel<<<(128 * 128 / 4 + 255) / 256, 256, 0, stream>>>(W2r, W2rb, 128 * 128 / 4);
    gemm_mfma_kernel<128, false, false, true, true, false><<<GB, 256, 0, stream>>>(
        aggB, hbT, W2lb, W2rb, b2, out);
}

// Round 6
// 326.599 us; speedup vs baseline: 1.7978x; 1.7978x over previous
//
#include <hip/hip_runtime.h>

#define NN 100000
#define NE 1600000
#define SCAN_BLK 2048

#define BSH 9                                  // 512 nodes/bucket
#define NBUCK2 ((NN + 511) / 512)              // 196 coarse buckets
#define CHUNK 8192                             // edges per partition block
#define NCHK ((NE + CHUNK - 1) / CHUNK)        // 196 chunks
#define L2T (NBUCK2 * NCHK)                    // 38416
#define NSTRIP (NN / 32)                       // 3125 exact

using bf16x8 = __attribute__((ext_vector_type(8))) short;
using f32x16 = __attribute__((ext_vector_type(16))) float;

// ---- bf16 helpers (RNE) ----
__device__ __forceinline__ unsigned short f2bf(float f) {
    unsigned u = __float_as_uint(f);
    u += 0x7FFFu + ((u >> 16) & 1u);
    return (unsigned short)(u >> 16);
}
__device__ __forceinline__ float bf2f(unsigned short h) {
    return __uint_as_float(((unsigned)h) << 16);
}

// ---------------- per-chunk bucket histogram (LDS only) ----------------
__global__ __launch_bounds__(256) void hist2_kernel(const int* __restrict__ dst,
                                                    int* __restrict__ histm) {
    __shared__ int lh[256];
    int blk = blockIdx.x, tid = threadIdx.x;
    lh[tid] = 0;
    __syncthreads();
    int base = blk * CHUNK;
#pragma unroll
    for (int t = 0; t < CHUNK / 256; t++) {
        int e = base + t * 256 + tid;
        if (e < NE) atomicAdd(&lh[dst[e] >> BSH], 1);
    }
    __syncthreads();
    if (tid < NBUCK2) histm[tid * NCHK + blk] = lh[tid];   // bucket-major
}

// ---------------- exclusive scan, stage 1 ----------------
__global__ __launch_bounds__(256) void scan1_kernel(int* __restrict__ data,
                                                    int* __restrict__ bsums, int L) {
    __shared__ int s[256];
    int bid = blockIdx.x, tid = threadIdx.x;
    int base = bid * SCAN_BLK + tid * 8;
    int v[8];
    int sum = 0;
#pragma unroll
    for (int t = 0; t < 8; t++) {
        int idx = base + t;
        v[t] = (idx < L) ? data[idx] : 0;
        sum += v[t];
    }
    s[tid] = sum;
    __syncthreads();
    for (int off = 1; off < 256; off <<= 1) {
        int val = (tid >= off) ? s[tid - off] : 0;
        __syncthreads();
        s[tid] += val;
        __syncthreads();
    }
    int excl = s[tid] - sum;
    if (tid == 255) bsums[bid] = s[255];
    int run = excl;
#pragma unroll
    for (int t = 0; t < 8; t++) {
        int idx = base + t;
        if (idx < L) data[idx] = run;
        run += v[t];
    }
}

// ---------------- scan stage 2: one wave over n<=64 sums ----------------
__global__ __launch_bounds__(64) void scan2_kernel(int* __restrict__ bsums, int n) {
    int tid = threadIdx.x;
    int orig = (tid < n) ? bsums[tid] : 0;
    int v = orig;
    for (int off = 1; off < 64; off <<= 1) {
        int nb = __shfl_up(v, off, 64);
        if (tid >= off) v += nb;
    }
    if (tid < n) bsums[tid] = v - orig;
}

// ---------------- add offsets (histm) ----------------
__global__ __launch_bounds__(256) void scan_add_kernel(int* __restrict__ data,
                                                       const int* __restrict__ bsums, int L) {
    int i = blockIdx.x * 256 + threadIdx.x;
    if (i < L) data[i] += bsums[i / SCAN_BLK];
}

// ---------------- deterministic coarse scatter (LDS cursors) ----------------
__global__ __launch_bounds__(256) void scatter2_kernel(const int* __restrict__ src,
                                                       const int* __restrict__ dst,
                                                       const int* __restrict__ histm,
                                                       int* __restrict__ tmp) {
    __shared__ int lcur[256];
    int blk = blockIdx.x, tid = threadIdx.x;
    if (tid < NBUCK2) lcur[tid] = histm[tid * NCHK + blk];
    __syncthreads();
    int base = blk * CHUNK;
#pragma unroll
    for (int t = 0; t < CHUNK / 256; t++) {
        int e = base + t * 256 + tid;
        if (e < NE) {
            int d = dst[e];
            int p = atomicAdd(&lcur[d >> BSH], 1);      // LDS atomic
            tmp[p] = src[e] | ((d & 511) << 17);        // src<2^17
        }
    }
}

// ---------------- fused count + scan + place per bucket ----------------
__global__ __launch_bounds__(256) void count_place_kernel(const int* __restrict__ histm,
                                                          const int* __restrict__ tmp,
                                                          int* __restrict__ rowptr,
                                                          int* __restrict__ esrc) {
    __shared__ int cnt[512];   // counts, then cursors
    __shared__ int s[256];
    int b = blockIdx.x, tid = threadIdx.x;
    int beg = histm[b * NCHK];
    int end = (b == NBUCK2 - 1) ? NE : histm[(b + 1) * NCHK];

    cnt[tid] = 0; cnt[tid + 256] = 0;
    __syncthreads();
    for (int e = beg + tid; e < end; e += 256)
        atomicAdd(&cnt[tmp[e] >> 17], 1);               // LDS atomic
    __syncthreads();

    int c0 = cnt[2 * tid], c1 = cnt[2 * tid + 1];
    int sum = c0 + c1;
    s[tid] = sum;
    __syncthreads();
    for (int off = 1; off < 256; off <<= 1) {
        int val = (tid >= off) ? s[tid - off] : 0;
        __syncthreads();
        s[tid] += val;
        __syncthreads();
    }
    int o0 = beg + s[tid] - sum;                        // exclusive
    int o1 = o0 + c0;
    cnt[2 * tid] = o0;                                  // cursors
    cnt[2 * tid + 1] = o1;
    int node0 = (b << BSH) + 2 * tid;
    if (node0 < NN)     rowptr[node0]     = o0;
    if (node0 + 1 < NN) rowptr[node0 + 1] = o1;
    if (b == 0 && tid == 0) rowptr[NN] = NE;
    __syncthreads();

    for (int e = beg + tid; e < end; e += 256) {
        int v = tmp[e];
        int p = atomicAdd(&cnt[v >> 17], 1);            // LDS atomic
        esrc[p] = v & 0x1FFFF;
    }
}

// ---------------- fp32 -> bf16 convert ----------------
__global__ __launch_bounds__(256) void cvt_kernel(const float* __restrict__ in,
                                                  unsigned short* __restrict__ out, int n4) {
    int i = blockIdx.x * 256 + threadIdx.x;
    if (i < n4) {
        float4 f = ((const float4*)in)[i];
        ((ushort4*)out)[i] = make_ushort4(f2bf(f.x), f2bf(f.y), f2bf(f.z), f2bf(f.w));
    }
}

// ---------------- bf16 mean-aggregate, K=64 ----------------
// Wave per node. 8 lanes/edge x 16B (bf16x8) = 128B row; 8 edges per load
// instruction; x2 unroll = 16 edges (2KB) in flight; deg~16 -> typical node
// completes the main loop in one iteration.
__global__ __launch_bounds__(256) void agg64_kernel(const unsigned short* __restrict__ feat,
                                                    const int* __restrict__ rowptr,
                                                    const int* __restrict__ esrc,
                                                    unsigned short* __restrict__ agg) {
    int node = blockIdx.x * 4 + (threadIdx.x >> 6);
    int lane = threadIdx.x & 63;
    int es = lane >> 3;            // edge slot 0..7
    int fi = lane & 7;             // feature block (8 bf16)
    int beg = rowptr[node], end = rowptr[node + 1];

    float ax[8];
#pragma unroll
    for (int i = 0; i < 8; i++) ax[i] = 0.0f;

    int e = beg;
    for (; e + 15 < end; e += 16) {
        int sA = esrc[e + es];
        int sB = esrc[e + 8 + es];
        bf16x8 uA = *(const bf16x8*)(feat + (size_t)sA * 64 + fi * 8);
        bf16x8 uB = *(const bf16x8*)(feat + (size_t)sB * 64 + fi * 8);
#pragma unroll
        for (int i = 0; i < 8; i++)
            ax[i] += bf2f((unsigned short)uA[i]) + bf2f((unsigned short)uB[i]);
    }
    if (e + 7 < end) {
        int s = esrc[e + es];
        bf16x8 u = *(const bf16x8*)(feat + (size_t)s * 64 + fi * 8);
#pragma unroll
        for (int i = 0; i < 8; i++) ax[i] += bf2f((unsigned short)u[i]);
        e += 8;
    }
    if (es < end - e) {
        int s = esrc[e + es];
        bf16x8 u = *(const bf16x8*)(feat + (size_t)s * 64 + fi * 8);
#pragma unroll
        for (int i = 0; i < 8; i++) ax[i] += bf2f((unsigned short)u[i]);
    }

#pragma unroll
    for (int i = 0; i < 8; i++) {
        ax[i] += __shfl_xor(ax[i], 8);
        ax[i] += __shfl_xor(ax[i], 16);
        ax[i] += __shfl_xor(ax[i], 32);
    }
    if (es == 0) {
        float inv = 1.0f / fmaxf((float)(end - beg), 1.0f);
        bf16x8 o;
#pragma unroll
        for (int i = 0; i < 8; i++) o[i] = (short)f2bf(ax[i] * inv);
        *(bf16x8*)(agg + (size_t)node * 64 + fi * 8) = o;
    }
}

// ---------------- bf16 mean-aggregate, K=128 ----------------
// Wave per node. 16 lanes/edge x 16B (bf16x8) = 256B row; 4 edges per load
// instruction. Deepened MLP (round 6): 16-edge main iteration = 4x16B loads
// in flight per lane; deg~16 -> typical node finishes main loop in ONE
// iteration. Reduce over edge-slots via shfl_xor(16/32).
__global__ __launch_bounds__(256) void agg128_kernel(const unsigned short* __restrict__ feat,
                                                     const int* __restrict__ rowptr,
                                                     const int* __restrict__ esrc,
                                                     unsigned short* __restrict__ agg) {
    int node = blockIdx.x * 4 + (threadIdx.x >> 6);
    int lane = threadIdx.x & 63;
    int es = lane >> 4;            // edge slot 0..3
    int fi = lane & 15;            // feature block (8 bf16)
    int beg = rowptr[node], end = rowptr[node + 1];

    float ax[8];
#pragma unroll
    for (int i = 0; i < 8; i++) ax[i] = 0.0f;

    int e = beg;
    for (; e + 15 < end; e += 16) {
        int s0 = esrc[e + es];
        int s1 = esrc[e + 4 + es];
        int s2 = esrc[e + 8 + es];
        int s3 = esrc[e + 12 + es];
        bf16x8 u0 = *(const bf16x8*)(feat + (size_t)s0 * 128 + fi * 8);
        bf16x8 u1 = *(const bf16x8*)(feat + (size_t)s1 * 128 + fi * 8);
        bf16x8 u2 = *(const bf16x8*)(feat + (size_t)s2 * 128 + fi * 8);
        bf16x8 u3 = *(const bf16x8*)(feat + (size_t)s3 * 128 + fi * 8);
#pragma unroll
        for (int i = 0; i < 8; i++)
            ax[i] += (bf2f((unsigned short)u0[i]) + bf2f((unsigned short)u1[i])) +
                     (bf2f((unsigned short)u2[i]) + bf2f((unsigned short)u3[i]));
    }
    for (; e + 3 < end; e += 4) {
        int s = esrc[e + es];
        bf16x8 u = *(const bf16x8*)(feat + (size_t)s * 128 + fi * 8);
#pragma unroll
        for (int i = 0; i < 8; i++) ax[i] += bf2f((unsigned short)u[i]);
    }
    if (es < end - e) {
        int s = esrc[e + es];
        bf16x8 u = *(const bf16x8*)(feat + (size_t)s * 128 + fi * 8);
#pragma unroll
        for (int i = 0; i < 8; i++) ax[i] += bf2f((unsigned short)u[i]);
    }

#pragma unroll
    for (int i = 0; i < 8; i++) {
        ax[i] += __shfl_xor(ax[i], 16);
        ax[i] += __shfl_xor(ax[i], 32);
    }
    if (es == 0) {
        float inv = 1.0f / fmaxf((float)(end - beg), 1.0f);
        bf16x8 o;
#pragma unroll
        for (int i = 0; i < 8; i++) o[i] = (short)f2bf(ax[i] * inv);
        *(bf16x8*)(agg + (size_t)node * 128 + fi * 8) = o;
    }
}

// ---------------- MFMA GEMM: out[n,0:128] = A1@Wa.T + A2@Wb.T + bias ----------------
// All operands bf16 row-major; fp32 accumulate in MFMA. One wave = 32-node
// strip x 128 outputs (4 acc tiles of 32x32x16). No LDS: A-frag is 8
// contiguous bf16 of the lane's own row (A[m=lane&31][k=half*8+j]); B-frag is
// 8 contiguous bf16 of W row n=lane&31 — W's natural [out][k] layout. C/D map
// (m74/m101-verified): col=lane&31, row=(reg&3)+8*(reg>>2)+4*half.
template <int K, bool RELU, bool OUTBF>
__global__ __launch_bounds__(256) void gemm_mfma_kernel(
    const unsigned short* __restrict__ A1,
    const unsigned short* __restrict__ A2,
    const unsigned short* __restrict__ Wa,
    const unsigned short* __restrict__ Wb,
    const float* __restrict__ bias,
    void* __restrict__ outv) {
    int strip = blockIdx.x * 4 + (threadIdx.x >> 6);
    if (strip >= NSTRIP) return;
    const int lane = threadIdx.x & 63;
    const int m = lane & 31;
    const int half = lane >> 5;
    const int base = strip * 32;

    f32x16 acc[4];
#pragma unroll
    for (int nb = 0; nb < 4; ++nb)
#pragma unroll
        for (int r = 0; r < 16; ++r) acc[nb][r] = 0.0f;

    const unsigned short* ar1 = A1 + (size_t)(base + m) * K + half * 8;
    const unsigned short* ar2 = A2 + (size_t)(base + m) * K + half * 8;
#pragma unroll
    for (int kc = 0; kc < K; kc += 16) {
        bf16x8 a = *(const bf16x8*)(ar1 + kc);
#pragma unroll
        for (int nb = 0; nb < 4; ++nb) {
            bf16x8 b = *(const bf16x8*)(Wa + (size_t)(nb * 32 + m) * K + kc + half * 8);
            acc[nb] = __builtin_amdgcn_mfma_f32_32x32x16_bf16(a, b, acc[nb], 0, 0, 0);
        }
    }
#pragma unroll
    for (int kc = 0; kc < K; kc += 16) {
        bf16x8 a = *(const bf16x8*)(ar2 + kc);
#pragma unroll
        for (int nb = 0; nb < 4; ++nb) {
            bf16x8 b = *(const bf16x8*)(Wb + (size_t)(nb * 32 + m) * K + kc + half * 8);
            acc[nb] = __builtin_amdgcn_mfma_f32_32x32x16_bf16(a, b, acc[nb], 0, 0, 0);
        }
    }

#pragma unroll
    for (int nb = 0; nb < 4; ++nb) {
        int j = nb * 32 + m;
        float bz = bias[j];
#pragma unroll
        for (int r = 0; r < 16; ++r) {
            int row = (r & 3) + 8 * (r >> 2) + 4 * half;
            float v = acc[nb][r] + bz;
            if (RELU) v = fmaxf(v, 0.0f);
            size_t idx = (size_t)(base + row) * 128 + j;
            if (OUTBF) ((unsigned short*)outv)[idx] = f2bf(v);
            else       ((float*)outv)[idx] = v;
        }
    }
}

extern "C" void kernel_launch(void* const* d_in, const int* in_sizes, int n_in,
                              void* d_out, int out_size, void* d_ws, size_t ws_size,
                              hipStream_t stream) {
    const float* x   = (const float*)d_in[0];
    const int*   ei  = (const int*)d_in[1];
    const float* W1l = (const float*)d_in[2];
    const float* W1r = (const float*)d_in[3];
    const float* b1  = (const float*)d_in[4];
    const float* W2l = (const float*)d_in[5];
    const float* W2r = (const float*)d_in[6];
    const float* b2  = (const float*)d_in[7];
    float* out = (float*)d_out;

    const int* src = ei;        // edge_index[0]
    const int* dst = ei + NE;   // edge_index[1]

    // ---- workspace layout ----
    char* ws = (char*)d_ws;
    int* rowptr = (int*)ws;                                  // [0, 401408)
    int* esrc   = (int*)(ws + 401408);                       // NE ints
    unsigned short* aggB = (unsigned short*)(ws + 6803456);  // NN*128 bf16 (25.6 MB)
    unsigned short* xb   = aggB + (size_t)NN * 64;           // NN*64 bf16, aggB upper half
    char* E = ws + 32403456;                                 // 25.6 MB region
    unsigned short* hb = (unsigned short*)E;                 // NN*128 bf16
    int* tmp   = (int*)E;                                    // NE ints (transient)
    int* histm = (int*)(E + 6400000);                        // L2T ints (transient)
    int* bsums = (int*)(E + 6560000);                        // <=64 ints (transient)
    // W bf16 copies:
    unsigned short* W1lb = (unsigned short*)d_out;           // 128*64 bf16 (16 KB)
    unsigned short* W1rb = W1lb + 128 * 64;
    unsigned short* W2lb = (unsigned short*)ws;              // 128*128 bf16 (32 KB), after agg128
    unsigned short* W2rb = W2lb + 128 * 128;

    const int GB  = (NSTRIP + 3) / 4;                        // 782 gemm blocks
    const int NSB2 = (L2T + SCAN_BLK - 1) / SCAN_BLK;        // 19

    // ---- build CSR (edge list sorted by dst); no global atomics ----
    hist2_kernel<<<NCHK, 256, 0, stream>>>(dst, histm);
    scan1_kernel<<<NSB2, 256, 0, stream>>>(histm, bsums, L2T);
    scan2_kernel<<<1, 64, 0, stream>>>(bsums, NSB2);
    scan_add_kernel<<<(L2T + 255) / 256, 256, 0, stream>>>(histm, bsums, L2T);
    scatter2_kernel<<<NCHK, 256, 0, stream>>>(src, dst, histm, tmp);
    count_place_kernel<<<NBUCK2, 256, 0, stream>>>(histm, tmp, rowptr, esrc);

    // ---- bf16 planes ----
    cvt_kernel<<<(NN * 64 / 4 + 255) / 256, 256, 0, stream>>>(x, xb, NN * 64 / 4);
    cvt_kernel<<<(128 * 64 / 4 + 255) / 256, 256, 0, stream>>>(W1l, W1lb, 128 * 64 / 4);
    cvt_kernel<<<(128 * 64 / 4 + 255) / 256, 256, 0, stream>>>(W1r, W1rb, 128 * 64 / 4);

    // ---- layer 1: hb = bf16(relu(mean(agg) @ W1l.T + x @ W1r.T + b1)) ----
    agg64_kernel<<<NN / 4, 256, 0, stream>>>(xb, rowptr, esrc, aggB);
    gemm_mfma_kernel<64, true, true><<<GB, 256, 0, stream>>>(aggB, xb, W1lb, W1rb, b1, hb);

    // ---- layer 2: out = mean(agg2) @ W2l.T + hb @ W2r.T + b2 ----
    agg128_kernel<<<NN / 4, 256, 0, stream>>>(hb, rowptr, esrc, aggB);  // kills xb; last use of esrc/rowptr
    cvt_kernel<<<(128 * 128 / 4 + 255) / 256, 256, 0, stream>>>(W2l, W2lb, 128 * 128 / 4);
    cvt_kernel<<<(128 * 128 / 4 + 255) / 256, 256, 0, stream>>>(W2r, W2rb, 128 * 128 / 4);
    gemm_mfma_kernel<128, false, false><<<GB, 256, 0, stream>>>(aggB, hb, W2lb, W2rb, b2, out);
}